// Round 8
// baseline (353.382 us; speedup 1.0000x reference)
//
#include <hip/hip_runtime.h>
#include <math.h>

#define S_LEN 2048
#define B_SZ 2
#define NHEAD 16
#define HDIM 64
#define H_DIM 1024
#define M_ROWS (S_LEN * B_SZ)   // 4096
#define LN_EPS 1e-5f
#define KSTR 72                  // attn LDS row stride (shorts): 2-way banks = free
#define SCL 0.18033688011112042f // 0.125 * log2(e)

typedef __attribute__((ext_vector_type(4))) float f32x4;
typedef __attribute__((ext_vector_type(8))) short short8;
typedef __attribute__((ext_vector_type(8))) unsigned short u16x8;
typedef __attribute__((ext_vector_type(4))) unsigned short u16x4;
typedef __attribute__((ext_vector_type(2))) unsigned short u16x2;

typedef __attribute__((address_space(3))) unsigned int lds_u32;
typedef const __attribute__((address_space(1))) unsigned int glb_u32;

#define ASM_VMCNT(N) asm volatile("s_waitcnt vmcnt(" #N ")" ::: "memory")

__device__ __forceinline__ float bf2f(unsigned short u) {
    return __uint_as_float(((unsigned int)u) << 16);
}
__device__ __forceinline__ unsigned short f2bf(float f) {
    unsigned int u = __float_as_uint(f);
    return (unsigned short)((u + 0x7fffu + ((u >> 16) & 1u)) >> 16);
}

// ---------------- fused weight cast fp32 -> bf16 (single launch) ------------
__global__ __launch_bounds__(256) void cast_all(const float* __restrict__ wqkv,
                                                const float* __restrict__ wproj,
                                                const float* __restrict__ wfc1,
                                                const float* __restrict__ wfc2,
                                                unsigned short* __restrict__ oqkv,
                                                unsigned short* __restrict__ oproj,
                                                unsigned short* __restrict__ ofc1,
                                                unsigned short* __restrict__ ofc2) {
    const int i = blockIdx.x * 256 + threadIdx.x;   // grid covers 3145728
    const float* src; unsigned short* dst; int off;
    if (i < 786432)       { src = wqkv;  dst = oqkv;  off = i; }
    else if (i < 1048576) { src = wproj; dst = oproj; off = i - 786432; }
    else if (i < 2097152) { src = wfc1;  dst = ofc1;  off = i - 1048576; }
    else                  { src = wfc2;  dst = ofc2;  off = i - 2097152; }
    f32x4 v = ((const f32x4*)src)[off];
    u16x4 o;
    o.x = f2bf(v.x); o.y = f2bf(v.y); o.z = f2bf(v.z); o.w = f2bf(v.w);
    ((u16x4*)dst)[off] = o;
}

// ---------------- LayerNorm row of 1024 -> bf16 -----------------------------
__global__ __launch_bounds__(256) void ln_bf16(const float* __restrict__ x,
                                               const float* __restrict__ w,
                                               const float* __restrict__ b,
                                               unsigned short* __restrict__ y) {
    const int m = blockIdx.x;
    const int tid = threadIdx.x;
    const float* row = x + (size_t)m * H_DIM;

    float4 v = ((const float4*)row)[tid];
    float s  = v.x + v.y + v.z + v.w;
    float ss = v.x * v.x + v.y * v.y + v.z * v.z + v.w * v.w;

    __shared__ float rs[4], rss[4], stats[2];
    const int wave = tid >> 6, lane = tid & 63;
    for (int off = 32; off; off >>= 1) {
        s  += __shfl_down(s, off);
        ss += __shfl_down(ss, off);
    }
    if (lane == 0) { rs[wave] = s; rss[wave] = ss; }
    __syncthreads();
    if (tid == 0) {
        float S = rs[0] + rs[1] + rs[2] + rs[3];
        float SS = rss[0] + rss[1] + rss[2] + rss[3];
        float mean = S * (1.0f / H_DIM);
        float var = SS * (1.0f / H_DIM) - mean * mean;
        stats[0] = mean;
        stats[1] = rsqrtf(var + LN_EPS);
    }
    __syncthreads();
    const float mean = stats[0], inv = stats[1];
    float4 wv = ((const float4*)w)[tid];
    float4 bv = ((const float4*)b)[tid];
    u16x4 o;
    o.x = f2bf((v.x - mean) * inv * wv.x + bv.x);
    o.y = f2bf((v.y - mean) * inv * wv.y + bv.y);
    o.z = f2bf((v.z - mean) * inv * wv.z + bv.z);
    o.w = f2bf((v.w - mean) * inv * wv.w + bv.w);
    ((u16x4*)(y + (size_t)m * H_DIM))[tid] = o;
}

// ---------------- bf16 MFMA GEMM v5 body: counted-vmcnt ring, BK=64 ---------
// C[M,N] = A[M,K] @ B[N,K]^T + bias. EPI: 0=bias, 1=+resid, 2=+gelu.
template <int EPI, bool BF_OUT, int TN>
__device__ __forceinline__ void gemm_body(const unsigned short* __restrict__ A,
                                          const unsigned short* __restrict__ B,
                                          const float* __restrict__ bias,
                                          const float* __restrict__ resid,
                                          void* __restrict__ Cout,
                                          int M, int N, int K) {
    constexpr int NJ  = TN / 32;               // n-frags per wave
    constexpr int ANI = 4;                     // A gload_lds issues per thread
    constexpr int BNI = TN / 32;               // B issues: 128->4, 64->2
    constexpr int NBUF = (TN == 128) ? 2 : 3;  // LDS ring depth
    __shared__ __attribute__((aligned(16))) unsigned short As[NBUF][128 * 64];
    __shared__ __attribute__((aligned(16))) unsigned short Bs[NBUF][TN * 64];

    const int tid = threadIdx.x;
    const int wid = tid >> 6;
    const int ln  = tid & 63;
    const int quad = ln >> 4;
    const int mr   = ln & 15;
    const int wm = (wid >> 1) * 64;
    const int wn = (wid & 1) * (TN / 2);

    const int mb = M >> 7;
    const int stripe = mb >> 3;               // 4 for M=4096
    const int xcd = blockIdx.x & 7;
    const int local = blockIdx.x >> 3;
    const int m0 = (xcd * stripe + (local % stripe)) << 7;
    const int n0 = (local / stripe) * TN;

    // staging geometry: wave w, issue i covers LDS rows {base + i*8 + lr},
    // lane writes bytes [lc*16, lc*16+16) of the row. Source column
    // pre-swizzled by ^(lr<<4); read side applies the same XOR.
    const int lr = ln >> 3, lc = ln & 7;
    const size_t Kb = (size_t)K * 2;          // row stride in bytes
    const char* gA = (const char*)A + (size_t)(m0 + wid * 32 + lr) * Kb
                     + (size_t)((lc << 4) ^ (lr << 4));
    const int bwr = (TN == 128) ? wid * 32 : wid * 16;
    const char* gB = (const char*)B + (size_t)(n0 + bwr + lr) * Kb
                     + (size_t)((lc << 4) ^ (lr << 4));

    auto stage = [&](int kt, int buf) {
        const char* pa = gA + (size_t)kt * 128;
        unsigned int* la = (unsigned int*)&As[buf][0] + wid * (ANI * 256);
#pragma unroll
        for (int i = 0; i < ANI; i++)
            __builtin_amdgcn_global_load_lds((glb_u32*)(pa + (size_t)i * 8 * Kb),
                                             (lds_u32*)(la + i * 256), 16, 0, 0);
        const char* pb = gB + (size_t)kt * 128;
        unsigned int* lb = (unsigned int*)&Bs[buf][0] + wid * (BNI * 256);
#pragma unroll
        for (int i = 0; i < BNI; i++)
            __builtin_amdgcn_global_load_lds((glb_u32*)(pb + (size_t)i * 8 * Kb),
                                             (lds_u32*)(lb + i * 256), 16, 0, 0);
    };

    const f32x4 zero = {0.f, 0.f, 0.f, 0.f};
    f32x4 acc[4][NJ];
#pragma unroll
    for (int i = 0; i < 4; i++)
#pragma unroll
        for (int j = 0; j < NJ; j++) acc[i][j] = zero;

    const int swz = (mr & 7) << 3;            // read-side XOR (shorts)
    auto compute = [&](const unsigned short* As_, const unsigned short* Bs_) {
#pragma unroll
        for (int h = 0; h < 2; h++) {
            short8 af[4], bfr[NJ];
#pragma unroll
            for (int i = 0; i < 4; i++)
                af[i] = *(const short8*)(As_ + (wm + i * 16 + mr) * 64
                                             + ((h * 32 + quad * 8) ^ swz));
#pragma unroll
            for (int j = 0; j < NJ; j++)
                bfr[j] = *(const short8*)(Bs_ + (wn + j * 16 + mr) * 64
                                              + ((h * 32 + quad * 8) ^ swz));
#pragma unroll
            for (int i = 0; i < 4; i++)
#pragma unroll
                for (int j = 0; j < NJ; j++)
                    acc[i][j] = __builtin_amdgcn_mfma_f32_16x16x32_bf16(bfr[j], af[i], acc[i][j], 0, 0, 0);
        }
    };

    const int nt = K >> 6;
    stage(0, 0);
    stage(1, 1);
    if (NBUF == 3) stage(2, 2);

    int cb = 0;
    for (int kt = 0; kt < nt; kt++) {
        if (NBUF == 3) {
            if (kt + 2 < nt)      ASM_VMCNT(12);
            else if (kt + 1 < nt) ASM_VMCNT(6);
            else                  ASM_VMCNT(0);
        } else {
            if (kt + 1 < nt)      ASM_VMCNT(8);
            else                  ASM_VMCNT(0);
        }
        __builtin_amdgcn_s_barrier();
        __builtin_amdgcn_sched_barrier(0);
        compute(&As[cb][0], &Bs[cb][0]);
        __builtin_amdgcn_sched_barrier(0);
        __builtin_amdgcn_s_barrier();
        if (kt + NBUF < nt) stage(kt + NBUF, cb);
        cb = (cb + 1 == NBUF) ? 0 : cb + 1;
    }

    f32x4 bias4[NJ];
#pragma unroll
    for (int j = 0; j < NJ; j++)
        bias4[j] = *(const f32x4*)(bias + n0 + wn + j * 16 + quad * 4);

#pragma unroll
    for (int i = 0; i < 4; i++) {
        const int m = m0 + wm + i * 16 + mr;
#pragma unroll
        for (int j = 0; j < NJ; j++) {
            const int nb = n0 + wn + j * 16 + quad * 4;
            f32x4 v = acc[i][j] + bias4[j];
            if (EPI == 1) v += *(const f32x4*)(resid + (size_t)m * N + nb);
            if (EPI == 2) {
#pragma unroll
                for (int r = 0; r < 4; r++) {
                    // gelu(tanh) via exp2: x*e/(e+1) written NaN-safe as x - x/(e+1)
                    const float t = v[r];
                    const float u = t + 0.044715f * t * t * t;
                    const float e = exp2f(2.3022112f * u);   // 2*log2(e)*0.79788456
                    v[r] = t - t / (e + 1.0f);
                }
            }
            if (BF_OUT) {
                u16x4 pk;
                pk.x = f2bf(v.x); pk.y = f2bf(v.y); pk.z = f2bf(v.z); pk.w = f2bf(v.w);
                *(u16x4*)((unsigned short*)Cout + (size_t)m * N + nb) = pk;
            } else {
                *(f32x4*)((float*)Cout + (size_t)m * N + nb) = v;
            }
        }
    }
}

// ---- named instantiations: one kernel symbol per op for rocprof attribution
__global__ __launch_bounds__(256) void gemm_qkv(const unsigned short* __restrict__ A,
                                                const unsigned short* __restrict__ B,
                                                const float* __restrict__ bias,
                                                void* __restrict__ Cout,
                                                int M, int N, int K) {
    gemm_body<0, true, 128>(A, B, bias, nullptr, Cout, M, N, K);
}
__global__ __launch_bounds__(256) void gemm_proj(const unsigned short* __restrict__ A,
                                                 const unsigned short* __restrict__ B,
                                                 const float* __restrict__ bias,
                                                 const float* __restrict__ resid,
                                                 void* __restrict__ Cout,
                                                 int M, int N, int K) {
    gemm_body<1, false, 64>(A, B, bias, resid, Cout, M, N, K);
}
__global__ __launch_bounds__(256) void gemm_fc1(const unsigned short* __restrict__ A,
                                                const unsigned short* __restrict__ B,
                                                const float* __restrict__ bias,
                                                void* __restrict__ Cout,
                                                int M, int N, int K) {
    gemm_body<2, true, 128>(A, B, bias, nullptr, Cout, M, N, K);
}
__global__ __launch_bounds__(256) void gemm_fc2(const unsigned short* __restrict__ A,
                                                const unsigned short* __restrict__ B,
                                                const float* __restrict__ bias,
                                                const float* __restrict__ resid,
                                                void* __restrict__ Cout,
                                                int M, int N, int K) {
    gemm_body<1, false, 64>(A, B, bias, resid, Cout, M, N, K);
}

// ---------------- fc2 split-K=2: workspace partials, NO atomics -------------
// Diagnosis (r7): fc2 is grid-limited (512 blocks = 2 blocks/CU = 25% wave
// cap); all schedule work was null because nothing can hide latency at 2
// waves/SIMD. r6's split-K failed on MECHANISM (serialized fp32 RMW atomics,
// 262MB WRITE) not on the parallelism idea. v2: each split s in {0,1} does
// K-window [s*K/2, (s+1)*K/2) with the UNCHANGED v5 TN=64 fragment+swizzle
// path, NBUF=2 (48 KB -> 3 blocks/CU), counted vmcnt(6), and writes an fp32
// partial to its own workspace buffer (bias folded into s=0). A separate
// add3 kernel does out += p0 + p1 (64 MB pure BW ~ 11 us).
__global__ __launch_bounds__(256) void gemm_fc2sk(const unsigned short* __restrict__ A,
                                                  const unsigned short* __restrict__ B,
                                                  const float* __restrict__ bias,
                                                  float* __restrict__ Pout,
                                                  int M, int N, int K) {
    constexpr int TN = 64, NJ = 2, ANI = 4, BNI = 2;
    __shared__ __attribute__((aligned(16))) unsigned short As[2][128 * 64];
    __shared__ __attribute__((aligned(16))) unsigned short Bs[2][64 * 64];

    const int tid = threadIdx.x;
    const int wid = tid >> 6;
    const int ln  = tid & 63;
    const int quad = ln >> 4;
    const int mr   = ln & 15;
    const int wm = (wid >> 1) * 64;
    const int wn = (wid & 1) * 32;

    // grid 1024: xcd(8) x [s(2) x n-tile(16) x m-stripe(4)]
    const int xcd = blockIdx.x & 7;
    const int local = blockIdx.x >> 3;        // 0..127
    const int s = local >> 6;                 // split index
    const int rem = local & 63;
    const int m0 = (xcd * 4 + (rem & 3)) << 7;
    const int n0 = (rem >> 2) * TN;

    const int Ks = K >> 1;                    // 2048
    const int lr = ln >> 3, lc = ln & 7;
    const size_t Kb = (size_t)K * 2;          // full row stride in bytes
    const char* gA = (const char*)A + (size_t)(m0 + wid * 32 + lr) * Kb
                     + (size_t)s * Ks * 2 + (size_t)((lc << 4) ^ (lr << 4));
    const char* gB = (const char*)B + (size_t)(n0 + wid * 16 + lr) * Kb
                     + (size_t)s * Ks * 2 + (size_t)((lc << 4) ^ (lr << 4));

    auto stage = [&](int kt, int buf) {
        const char* pa = gA + (size_t)kt * 128;
        unsigned int* la = (unsigned int*)&As[buf][0] + wid * (ANI * 256);
#pragma unroll
        for (int i = 0; i < ANI; i++)
            __builtin_amdgcn_global_load_lds((glb_u32*)(pa + (size_t)i * 8 * Kb),
                                             (lds_u32*)(la + i * 256), 16, 0, 0);
        const char* pb = gB + (size_t)kt * 128;
        unsigned int* lb = (unsigned int*)&Bs[buf][0] + wid * (BNI * 256);
#pragma unroll
        for (int i = 0; i < BNI; i++)
            __builtin_amdgcn_global_load_lds((glb_u32*)(pb + (size_t)i * 8 * Kb),
                                             (lds_u32*)(lb + i * 256), 16, 0, 0);
    };

    const f32x4 zero = {0.f, 0.f, 0.f, 0.f};
    f32x4 acc[4][NJ];
#pragma unroll
    for (int i = 0; i < 4; i++)
#pragma unroll
        for (int j = 0; j < NJ; j++) acc[i][j] = zero;

    const int swz = (mr & 7) << 3;
    auto compute = [&](const unsigned short* As_, const unsigned short* Bs_) {
#pragma unroll
        for (int h = 0; h < 2; h++) {
            short8 af[4], bfr[NJ];
#pragma unroll
            for (int i = 0; i < 4; i++)
                af[i] = *(const short8*)(As_ + (wm + i * 16 + mr) * 64
                                             + ((h * 32 + quad * 8) ^ swz));
#pragma unroll
            for (int j = 0; j < NJ; j++)
                bfr[j] = *(const short8*)(Bs_ + (wn + j * 16 + mr) * 64
                                              + ((h * 32 + quad * 8) ^ swz));
#pragma unroll
            for (int i = 0; i < 4; i++)
#pragma unroll
                for (int j = 0; j < NJ; j++)
                    acc[i][j] = __builtin_amdgcn_mfma_f32_16x16x32_bf16(bfr[j], af[i], acc[i][j], 0, 0, 0);
        }
    };

    const int nt = Ks >> 6;                   // 32
    stage(0, 0);
    stage(1, 1);
    for (int kt = 0; kt < nt; kt++) {
        if (kt + 1 < nt) ASM_VMCNT(6); else ASM_VMCNT(0);
        __builtin_amdgcn_s_barrier();
        __builtin_amdgcn_sched_barrier(0);
        compute(&As[kt & 1][0], &Bs[kt & 1][0]);
        __builtin_amdgcn_sched_barrier(0);
        __builtin_amdgcn_s_barrier();
        if (kt + 2 < nt) stage(kt + 2, kt & 1);
    }

    float* P = Pout + (size_t)s * M * N;
    f32x4 bias4[NJ];
#pragma unroll
    for (int j = 0; j < NJ; j++)
        bias4[j] = (s == 0) ? *(const f32x4*)(bias + n0 + wn + j * 16 + quad * 4) : zero;

#pragma unroll
    for (int i = 0; i < 4; i++) {
        const int m = m0 + wm + i * 16 + mr;
#pragma unroll
        for (int j = 0; j < NJ; j++) {
            const int nb = n0 + wn + j * 16 + quad * 4;
            *(f32x4*)(P + (size_t)m * N + nb) = acc[i][j] + bias4[j];
        }
    }
}

// out += p0 + p1 (grid-stride float4)
__global__ __launch_bounds__(256) void add3(float* __restrict__ out,
                                            const float* __restrict__ p0,
                                            const float* __restrict__ p1,
                                            int n4) {
    for (int i = blockIdx.x * 256 + threadIdx.x; i < n4; i += gridDim.x * 256) {
        f32x4 v = ((const f32x4*)p0)[i] + ((const f32x4*)p1)[i] + ((f32x4*)out)[i];
        ((f32x4*)out)[i] = v;
    }
}

// ---------------- MFMA flash attention v3 -----------------------------------
// XCD-local (K/V in XCD L2), reg-prefetch staging, max-free softmax.
__global__ __launch_bounds__(256) void attn_mfma(const unsigned short* __restrict__ qkv,
                                                 unsigned short* __restrict__ out) {
    __shared__ __attribute__((aligned(16))) unsigned short Ks[64 * KSTR];
    __shared__ __attribute__((aligned(16))) unsigned short Vs[64 * KSTR];
    __shared__ __attribute__((aligned(16))) unsigned short Ps[64 * KSTR];

    const int tid = threadIdx.x;
    const int wid = tid >> 6;
    const int ln  = tid & 63;
    const int quad = ln >> 4;
    const int mr   = ln & 15;

    const int id = blockIdx.x;                 // 0..511
    const int local = id >> 3;                 // 0..63
    const int bh = (id & 7) * 4 + (local >> 4);
    const int pa = local & 15;
    const int b  = bh >> 4;
    const int nh = bh & 15;
    const size_t chan = (size_t)nh * 192;

    const int ksr = tid >> 2, ksc = tid & 3;
    const int vt0 = (tid & 31) * 2, vd0 = (tid >> 5) * 8;

    u16x8 kp0, kp1, vp0, vp1;   // prefetch registers

#pragma unroll
    for (int half = 0; half < 2; half++) {
        const int qt = half ? (31 - pa) : pa;
        const int qb = qt * 64;

        short8 qf0, qf1;
        {
            const int qrow = qb + wid * 16 + mr;
            const unsigned short* gq = qkv + ((size_t)(qrow * 2 + b)) * 3072 + chan + quad * 8;
            qf0 = *(const short8*)gq;
            qf1 = *(const short8*)(gq + 32);
        }

        const f32x4 zero = {0.f, 0.f, 0.f, 0.f};
        f32x4 o[4];
        float ps = 0.f;
#pragma unroll
        for (int d = 0; d < 4; d++) o[d] = zero;

        {
            const unsigned short* gk = qkv + ((size_t)(ksr * 2 + b)) * 3072 + chan + 64 + ksc * 16;
            kp0 = *(const u16x8*)gk;
            kp1 = *(const u16x8*)(gk + 8);
            const unsigned short* gv = qkv + ((size_t)(vt0 * 2 + b)) * 3072 + chan + 128 + vd0;
            vp0 = *(const u16x8*)gv;
            vp1 = *(const u16x8*)(gv + 6144);
        }

        for (int kt = 0; kt <= qt; kt++) {
            __syncthreads();
            *(u16x8*)(Ks + ksr * KSTR + ksc * 16) = kp0;
            *(u16x8*)(Ks + ksr * KSTR + ksc * 16 + 8) = kp1;
#pragma unroll
            for (int j = 0; j < 8; j++) {
                u16x2 pr; pr.x = vp0[j]; pr.y = vp1[j];
                *(u16x2*)(Vs + (vd0 + j) * KSTR + vt0) = pr;
            }
            if (kt < qt) {
                const int nb = (kt + 1) * 64;
                const unsigned short* gk =
                    qkv + ((size_t)((nb + ksr) * 2 + b)) * 3072 + chan + 64 + ksc * 16;
                kp0 = *(const u16x8*)gk;
                kp1 = *(const u16x8*)(gk + 8);
                const unsigned short* gv =
                    qkv + ((size_t)((nb + vt0) * 2 + b)) * 3072 + chan + 128 + vd0;
                vp0 = *(const u16x8*)gv;
                vp1 = *(const u16x8*)(gv + 6144);
            }
            __syncthreads();

            // ---- S^T = K Q^T: lane owns q=mr, t = n*16 + quad*4 + r ----
            f32x4 sacc[4];
#pragma unroll
            for (int n = 0; n < 4; n++) {
                sacc[n] = zero;
                const unsigned short* kb = Ks + (n * 16 + mr) * KSTR + quad * 8;
                short8 kfr0 = *(const short8*)kb;
                short8 kfr1 = *(const short8*)(kb + 32);
                sacc[n] = __builtin_amdgcn_mfma_f32_16x16x32_bf16(kfr0, qf0, sacc[n], 0, 0, 0);
                sacc[n] = __builtin_amdgcn_mfma_f32_16x16x32_bf16(kfr1, qf1, sacc[n], 0, 0, 0);
            }
            if (kt == qt) {
#pragma unroll
                for (int n = 0; n < 4; n++)
#pragma unroll
                    for (int r = 0; r < 4; r++)
                        if (n * 16 + quad * 4 + r > wid * 16 + mr) sacc[n][r] = -3.0e38f;
            }

            // ---- max-free softmax: p = 2^(s*SCL), clamped; fp32 row-partials ----
            unsigned short* prow = Ps + (wid * 16 + mr) * KSTR + quad * 4;
#pragma unroll
            for (int n = 0; n < 4; n++) {
                u16x4 pk;
#pragma unroll
                for (int r = 0; r < 4; r++) {
                    const float p = exp2f(fminf(sacc[n][r] * SCL, 80.f));
                    ps += p;
                    pk[r] = (unsigned short)(__float_as_uint(p) >> 16);
                }
                *(u16x4*)(prow + n * 16) = pk;
            }

            // ---- O^T += V^T P^T: lane owns q=mr, d = dblk*16 + quad*4 + r ----
            {
                const unsigned short* pb = Ps + (wid * 16 + mr) * KSTR + quad * 8;
                short8 pa0 = *(const short8*)pb;
                short8 pa1 = *(const short8*)(pb + 32);
#pragma unroll
                for (int d = 0; d < 4; d++) {
                    const unsigned short* vb = Vs + (d * 16 + mr) * KSTR + quad * 8;
                    short8 vf0 = *(const short8*)vb;
                    short8 vf1 = *(const short8*)(vb + 32);
                    o[d] = __builtin_amdgcn_mfma_f32_16x16x32_bf16(vf0, pa0, o[d], 0, 0, 0);
                    o[d] = __builtin_amdgcn_mfma_f32_16x16x32_bf16(vf1, pa1, o[d], 0, 0, 0);
                }
            }
        }

        // ---- epilogue: l[q=mr] via 2 shfl_xor; vectorized O store ----
        ps += __shfl_xor(ps, 16);
        ps += __shfl_xor(ps, 32);
        const float inv = 1.0f / ps;
        const int qrow = qb + wid * 16 + mr;
        unsigned short* po = out + ((size_t)(qrow * 2 + b)) * H_DIM + nh * HDIM;
#pragma unroll
        for (int d = 0; d < 4; d++) {
            u16x4 pk;
#pragma unroll
            for (int r = 0; r < 4; r++) pk[r] = f2bf(o[d][r] * inv);
            *(u16x4*)(po + d * 16 + quad * 4) = pk;
        }
    }
}

extern "C" void kernel_launch(void* const* d_in, const int* in_sizes, int n_in,
                              void* d_out, int out_size, void* d_ws, size_t ws_size,
                              hipStream_t stream) {
    const float* x      = (const float*)d_in[0];
    const float* ln1_w  = (const float*)d_in[1];
    const float* ln1_b  = (const float*)d_in[2];
    const float* w_qkv  = (const float*)d_in[3];
    const float* b_qkv  = (const float*)d_in[4];
    const float* w_proj = (const float*)d_in[5];
    const float* b_proj = (const float*)d_in[6];
    const float* ln2_w  = (const float*)d_in[7];
    const float* ln2_b  = (const float*)d_in[8];
    const float* w_fc1  = (const float*)d_in[9];
    const float* b_fc1  = (const float*)d_in[10];
    const float* w_fc2  = (const float*)d_in[11];
    const float* b_fc2  = (const float*)d_in[12];
    float* out = (float*)d_out;

    char* ws = (char*)d_ws;
    unsigned short* wqkv_bf  = (unsigned short*)(ws);                        // 6 MB
    unsigned short* wproj_bf = (unsigned short*)(ws + ((size_t)6 << 20));    // 2 MB
    unsigned short* wfc1_bf  = (unsigned short*)(ws + ((size_t)8 << 20));    // 8 MB
    unsigned short* wfc2_bf  = (unsigned short*)(ws + ((size_t)16 << 20));   // 8 MB
    unsigned short* ln_buf   = (unsigned short*)(ws + ((size_t)24 << 20));   // 8 MB
    unsigned short* qkv_bf   = (unsigned short*)(ws + ((size_t)32 << 20));   // 24 MB
    unsigned short* attn_bf  = (unsigned short*)(ws + ((size_t)56 << 20));   // 8 MB
    unsigned short* fc1_bf   = (unsigned short*)(ws + ((size_t)32 << 20));   // 32 MB (qkv/attn dead)
    float* fc2_part = (float*)(ws + ((size_t)64 << 20));                     // 32 MB (2x fp32 partials)

    cast_all<<<12288, 256, 0, stream>>>(w_qkv, w_proj, w_fc1, w_fc2,
                                        wqkv_bf, wproj_bf, wfc1_bf, wfc2_bf);

    // 1) LN1 -> bf16
    ln_bf16<<<M_ROWS, 256, 0, stream>>>(x, ln1_w, ln1_b, ln_buf);
    // 2) qkv = ln1 @ w_qkv^T + b_qkv   [4096,3072] bf16   (768 blocks)
    gemm_qkv<<<768, 256, 0, stream>>>(ln_buf, wqkv_bf, b_qkv, qkv_bf,
                                      M_ROWS, 3072, 1024);
    // 3) MFMA flash attention -> bf16 [4096,1024]   (512 blocks, XCD-local)
    attn_mfma<<<512, 256, 0, stream>>>(qkv_bf, attn_bf);
    // 4) x1 = x + attn @ w_proj^T + b_proj  -> d_out (fp32)   (512 blocks)
    gemm_proj<<<512, 256, 0, stream>>>(attn_bf, wproj_bf, b_proj, x, out,
                                       M_ROWS, 1024, 1024);
    // 5) LN2 -> bf16
    ln_bf16<<<M_ROWS, 256, 0, stream>>>(out, ln2_w, ln2_b, ln_buf);
    // 6) fc1 + gelu -> bf16 [4096,4096]   (1024 blocks)
    gemm_fc1<<<1024, 256, 0, stream>>>(ln_buf, wfc1_bf, b_fc1, fc1_bf,
                                       M_ROWS, 4096, 1024);
    // 7) fc2 split-K=2 -> fp32 partials (1024 blocks, 3 blocks/CU), then
    //    out(x1) += p0 + p1. Falls back to fused path if ws too small.
    if (ws_size >= ((size_t)96 << 20)) {
        gemm_fc2sk<<<1024, 256, 0, stream>>>(fc1_bf, wfc2_bf, b_fc2, fc2_part,
                                             M_ROWS, 1024, 4096);
        add3<<<2048, 256, 0, stream>>>(out, fc2_part,
                                       fc2_part + (size_t)M_ROWS * 1024,
                                       (M_ROWS * 1024) / 4);
    } else {
        gemm_fc2<<<512, 256, 0, stream>>>(fc1_bf, wfc2_bf, b_fc2, out, out,
                                          M_ROWS, 1024, 4096);
    }
}

// Round 9
// 331.535 us; speedup vs baseline: 1.0659x; 1.0659x over previous
//
#include <hip/hip_runtime.h>
#include <math.h>

#define S_LEN 2048
#define B_SZ 2
#define NHEAD 16
#define HDIM 64
#define H_DIM 1024
#define M_ROWS (S_LEN * B_SZ)   // 4096
#define LN_EPS 1e-5f
#define KSTR 72                  // attn LDS row stride (shorts): 2-way banks = free
#define SCL 0.18033688011112042f // 0.125 * log2(e)

typedef __attribute__((ext_vector_type(4))) float f32x4;
typedef __attribute__((ext_vector_type(8))) short short8;
typedef __attribute__((ext_vector_type(8))) unsigned short u16x8;
typedef __attribute__((ext_vector_type(4))) unsigned short u16x4;
typedef __attribute__((ext_vector_type(2))) unsigned short u16x2;

typedef __attribute__((address_space(3))) unsigned int lds_u32;
typedef const __attribute__((address_space(1))) unsigned int glb_u32;

#define ASM_VMCNT(N) asm volatile("s_waitcnt vmcnt(" #N ")" ::: "memory")

__device__ __forceinline__ float bf2f(unsigned short u) {
    return __uint_as_float(((unsigned int)u) << 16);
}
__device__ __forceinline__ unsigned short f2bf(float f) {
    unsigned int u = __float_as_uint(f);
    return (unsigned short)((u + 0x7fffu + ((u >> 16) & 1u)) >> 16);
}

// ---------------- weight cast + pack into MFMA-fragment-linear layout -------
// Fragment = 16 n-rows x 32 k (one 16x16x32 B-operand): packed[frag][lane][8]
// = W[nt*16 + (lane&15)][kc*32 + (lane>>4)*8 + e]  (exactly the bytes the old
// LDS path delivered to bfr). GEMM loads a fragment as ONE coalesced 1KB
// global_load_dwordx4 per wave -> B never touches LDS.
// frag ranges: qkv 6144 | proj 2048 | fc1 8192 | fc2 8192 (total 24576).
__global__ __launch_bounds__(256) void cast_pack(const float* __restrict__ wqkv,
                                                 const float* __restrict__ wproj,
                                                 const float* __restrict__ wfc1,
                                                 const float* __restrict__ wfc2,
                                                 unsigned short* __restrict__ oqkv,
                                                 unsigned short* __restrict__ oproj,
                                                 unsigned short* __restrict__ ofc1,
                                                 unsigned short* __restrict__ ofc2) {
    const int t = blockIdx.x * 256 + threadIdx.x;   // 6144 blocks
    const int fi = t >> 6, l = t & 63;
    const float* src; unsigned short* dst; int KC, lf;
    if (fi < 6144)       { src = wqkv;  dst = oqkv;  KC = 32;  lf = fi; }
    else if (fi < 8192)  { src = wproj; dst = oproj; KC = 32;  lf = fi - 6144; }
    else if (fi < 16384) { src = wfc1;  dst = ofc1;  KC = 32;  lf = fi - 8192; }
    else                 { src = wfc2;  dst = ofc2;  KC = 128; lf = fi - 16384; }
    const int K = KC * 32;
    const int nt = lf / KC, kc = lf - nt * KC;
    const float* p = src + (size_t)(nt * 16 + (l & 15)) * K + kc * 32 + (l >> 4) * 8;
    f32x4 a = *(const f32x4*)p;
    f32x4 b = *(const f32x4*)(p + 4);
    u16x8 o;
    o[0] = f2bf(a.x); o[1] = f2bf(a.y); o[2] = f2bf(a.z); o[3] = f2bf(a.w);
    o[4] = f2bf(b.x); o[5] = f2bf(b.y); o[6] = f2bf(b.z); o[7] = f2bf(b.w);
    *(u16x8*)(dst + ((size_t)lf * 64 + l) * 8) = o;
}

// ---------------- LayerNorm row of 1024 -> bf16 -----------------------------
__global__ __launch_bounds__(256) void ln_bf16(const float* __restrict__ x,
                                               const float* __restrict__ w,
                                               const float* __restrict__ b,
                                               unsigned short* __restrict__ y) {
    const int m = blockIdx.x;
    const int tid = threadIdx.x;
    const float* row = x + (size_t)m * H_DIM;

    float4 v = ((const float4*)row)[tid];
    float s  = v.x + v.y + v.z + v.w;
    float ss = v.x * v.x + v.y * v.y + v.z * v.z + v.w * v.w;

    __shared__ float rs[4], rss[4], stats[2];
    const int wave = tid >> 6, lane = tid & 63;
    for (int off = 32; off; off >>= 1) {
        s  += __shfl_down(s, off);
        ss += __shfl_down(ss, off);
    }
    if (lane == 0) { rs[wave] = s; rss[wave] = ss; }
    __syncthreads();
    if (tid == 0) {
        float S = rs[0] + rs[1] + rs[2] + rs[3];
        float SS = rss[0] + rss[1] + rss[2] + rss[3];
        float mean = S * (1.0f / H_DIM);
        float var = SS * (1.0f / H_DIM) - mean * mean;
        stats[0] = mean;
        stats[1] = rsqrtf(var + LN_EPS);
    }
    __syncthreads();
    const float mean = stats[0], inv = stats[1];
    float4 wv = ((const float4*)w)[tid];
    float4 bv = ((const float4*)b)[tid];
    u16x4 o;
    o.x = f2bf((v.x - mean) * inv * wv.x + bv.x);
    o.y = f2bf((v.y - mean) * inv * wv.y + bv.y);
    o.z = f2bf((v.z - mean) * inv * wv.z + bv.z);
    o.w = f2bf((v.w - mean) * inv * wv.w + bv.w);
    ((u16x4*)(y + (size_t)m * H_DIM))[tid] = o;
}

// ---------------- bf16 MFMA GEMM v9: A via LDS, B direct-to-VGPR ------------
// Diagnosis (r8): per-CU throughput invariant across schedule/occupancy/
// split-K => LDS pipe saturated (72 KB/block-step = 64 B/cyc ~ ceiling).
// v9 removes B from LDS: fragment-packed weights (cast_pack) are loaded as
// one coalesced 1KB global_load per fragment into VGPRs, double-buffered
// across K-steps (full iteration of L2 cover). A path unchanged from r7
// (global_load_lds + XOR swizzle both sides). LDS/block-step 72->48 KB
// (TN=64), 96->64 KB (TN=128); LDS 32 KB -> up to 5 blocks/CU.
// vmcnt ledger (per thread): stage=4 ops, loadB=2*NJ ops. Steady top-of-step
// outstanding: loadB(kt)[B_I] + stage(kt+1)[4]; manual vmcnt(B_I+4) forces
// stage(kt) (oldest) only. Compiler's auto-wait for B-regs counts the newer
// in-flight ops exactly (it tracks global_load_lds in its vmcnt model).
template <int EPI, bool BF_OUT, int TN>
__device__ __forceinline__ void gemm_body(const unsigned short* __restrict__ A,
                                          const unsigned short* __restrict__ Bp,
                                          const float* __restrict__ bias,
                                          const float* __restrict__ resid,
                                          void* __restrict__ Cout,
                                          int M, int N, int K) {
    constexpr int NJ = TN / 32;                // n-frags per wave per h
    __shared__ __attribute__((aligned(16))) unsigned short As[2][128 * 64];  // 32 KB

    const int tid = threadIdx.x;
    const int wid = tid >> 6;
    const int ln  = tid & 63;
    const int quad = ln >> 4;
    const int mr   = ln & 15;
    const int wm = (wid >> 1) * 64;
    const int wn = (wid & 1) * (TN / 2);

    const int mb = M >> 7;
    const int stripe = mb >> 3;               // 4 for M=4096
    const int xcd = blockIdx.x & 7;
    const int local = blockIdx.x >> 3;
    const int m0 = (xcd * stripe + (local % stripe)) << 7;
    const int n0 = (local / stripe) * TN;

    // A staging (unchanged, verified): wave w issue i covers rows w*32+i*8+lr,
    // lane writes 16B at col lc*16; source col pre-swizzled ^(lr<<4).
    const int lr = ln >> 3, lc = ln & 7;
    const size_t Kb = (size_t)K * 2;
    const char* gA = (const char*)A + (size_t)(m0 + wid * 32 + lr) * Kb
                     + (size_t)((lc << 4) ^ (lr << 4));

    auto stage = [&](int kt, int buf) {
        const char* pa = gA + (size_t)kt * 128;
        unsigned int* la = (unsigned int*)&As[buf][0] + wid * (4 * 256);
#pragma unroll
        for (int i = 0; i < 4; i++)
            __builtin_amdgcn_global_load_lds((glb_u32*)(pa + (size_t)i * 8 * Kb),
                                             (lds_u32*)(la + i * 256), 16, 0, 0);
    };

    // B fragments from packed weights: frag idx = (n/16)*KC + (k/32).
    const int KC = K >> 5;
    const unsigned short* gBp = Bp + ((size_t)((n0 + wn) >> 4) * KC * 64 + ln) * 8;
    auto loadB = [&](int kt, u16x8 (&bb)[NJ][2]) {
#pragma unroll
        for (int j = 0; j < NJ; j++)
#pragma unroll
            for (int h = 0; h < 2; h++)
                bb[j][h] = *(const u16x8*)(gBp
                              + ((size_t)j * KC + (kt * 2 + h)) * 64 * 8);
    };

    const f32x4 zero = {0.f, 0.f, 0.f, 0.f};
    f32x4 acc[4][NJ];
#pragma unroll
    for (int i = 0; i < 4; i++)
#pragma unroll
        for (int j = 0; j < NJ; j++) acc[i][j] = zero;

    const int swz = (mr & 7) << 3;            // read-side XOR (shorts)
    auto compute = [&](const unsigned short* As_, u16x8 (&bc)[NJ][2]) {
#pragma unroll
        for (int h = 0; h < 2; h++) {
            short8 af[4];
#pragma unroll
            for (int i = 0; i < 4; i++)
                af[i] = *(const short8*)(As_ + (wm + i * 16 + mr) * 64
                                             + ((h * 32 + quad * 8) ^ swz));
#pragma unroll
            for (int i = 0; i < 4; i++)
#pragma unroll
                for (int j = 0; j < NJ; j++)
                    acc[i][j] = __builtin_amdgcn_mfma_f32_16x16x32_bf16(
                        (short8)bc[j][h], af[i], acc[i][j], 0, 0, 0);
        }
    };

    u16x8 bA[NJ][2], bB[NJ][2];               // static names (rule #20)
    const int nt = K >> 6;                    // 16 or 64: always even
    stage(0, 0);
    stage(1, 1);
    loadB(0, bA);

    for (int kt = 0; kt < nt; kt += 2) {
        // ---- even step: tile kt in As[0], B in bA ----
        if (kt + 1 < nt) {                    // allow loadB(kt)+stage(kt+1)
            if (TN == 128) ASM_VMCNT(12); else ASM_VMCNT(8);
        } else {
            if (TN == 128) ASM_VMCNT(8);  else ASM_VMCNT(4);
        }
        __builtin_amdgcn_s_barrier();         // tile kt visible to all
        if (kt + 1 < nt) loadB(kt + 1, bB);   // full step of L2 cover
        __builtin_amdgcn_sched_barrier(0);
        compute(&As[0][0], bA);
        __builtin_amdgcn_sched_barrier(0);
        __builtin_amdgcn_s_barrier();         // all waves done reading As[0]
        if (kt + 2 < nt) stage(kt + 2, 0);
        // ---- odd step: tile kt+1 in As[1], B in bB ----
        if (kt + 2 < nt) {
            if (TN == 128) ASM_VMCNT(12); else ASM_VMCNT(8);
        } else {
            if (TN == 128) ASM_VMCNT(8);  else ASM_VMCNT(4);
        }
        __builtin_amdgcn_s_barrier();
        if (kt + 2 < nt) loadB(kt + 2, bA);
        __builtin_amdgcn_sched_barrier(0);
        compute(&As[1][0], bB);
        __builtin_amdgcn_sched_barrier(0);
        __builtin_amdgcn_s_barrier();
        if (kt + 3 < nt) stage(kt + 3, 1);
    }

    // epilogue (unchanged)
    f32x4 bias4[NJ];
#pragma unroll
    for (int j = 0; j < NJ; j++)
        bias4[j] = *(const f32x4*)(bias + n0 + wn + j * 16 + quad * 4);

#pragma unroll
    for (int i = 0; i < 4; i++) {
        const int m = m0 + wm + i * 16 + mr;
#pragma unroll
        for (int j = 0; j < NJ; j++) {
            const int nb = n0 + wn + j * 16 + quad * 4;
            f32x4 v = acc[i][j] + bias4[j];
            if (EPI == 1) v += *(const f32x4*)(resid + (size_t)m * N + nb);
            if (EPI == 2) {
#pragma unroll
                for (int r = 0; r < 4; r++) {
                    // gelu(tanh) via exp2: x*e/(e+1) written NaN-safe as x - x/(e+1)
                    const float t = v[r];
                    const float u = t + 0.044715f * t * t * t;
                    const float e = exp2f(2.3022112f * u);   // 2*log2(e)*0.79788456
                    v[r] = t - t / (e + 1.0f);
                }
            }
            if (BF_OUT) {
                u16x4 pk;
                pk.x = f2bf(v.x); pk.y = f2bf(v.y); pk.z = f2bf(v.z); pk.w = f2bf(v.w);
                *(u16x4*)((unsigned short*)Cout + (size_t)m * N + nb) = pk;
            } else {
                *(f32x4*)((float*)Cout + (size_t)m * N + nb) = v;
            }
        }
    }
}

// ---- named instantiations: one kernel symbol per op for rocprof attribution
__global__ __launch_bounds__(256) void gemm_qkv(const unsigned short* __restrict__ A,
                                                const unsigned short* __restrict__ B,
                                                const float* __restrict__ bias,
                                                void* __restrict__ Cout,
                                                int M, int N, int K) {
    gemm_body<0, true, 128>(A, B, bias, nullptr, Cout, M, N, K);
}
__global__ __launch_bounds__(256) void gemm_proj(const unsigned short* __restrict__ A,
                                                 const unsigned short* __restrict__ B,
                                                 const float* __restrict__ bias,
                                                 const float* __restrict__ resid,
                                                 void* __restrict__ Cout,
                                                 int M, int N, int K) {
    gemm_body<1, false, 64>(A, B, bias, resid, Cout, M, N, K);
}
__global__ __launch_bounds__(256) void gemm_fc1(const unsigned short* __restrict__ A,
                                                const unsigned short* __restrict__ B,
                                                const float* __restrict__ bias,
                                                void* __restrict__ Cout,
                                                int M, int N, int K) {
    gemm_body<2, true, 128>(A, B, bias, nullptr, Cout, M, N, K);
}
__global__ __launch_bounds__(256) void gemm_fc2(const unsigned short* __restrict__ A,
                                                const unsigned short* __restrict__ B,
                                                const float* __restrict__ bias,
                                                const float* __restrict__ resid,
                                                void* __restrict__ Cout,
                                                int M, int N, int K) {
    gemm_body<1, false, 64>(A, B, bias, resid, Cout, M, N, K);
}

// ---------------- MFMA flash attention v3 -----------------------------------
// XCD-local (K/V in XCD L2), reg-prefetch staging, max-free softmax.
__global__ __launch_bounds__(256) void attn_mfma(const unsigned short* __restrict__ qkv,
                                                 unsigned short* __restrict__ out) {
    __shared__ __attribute__((aligned(16))) unsigned short Ks[64 * KSTR];
    __shared__ __attribute__((aligned(16))) unsigned short Vs[64 * KSTR];
    __shared__ __attribute__((aligned(16))) unsigned short Ps[64 * KSTR];

    const int tid = threadIdx.x;
    const int wid = tid >> 6;
    const int ln  = tid & 63;
    const int quad = ln >> 4;
    const int mr   = ln & 15;

    const int id = blockIdx.x;                 // 0..511
    const int local = id >> 3;                 // 0..63
    const int bh = (id & 7) * 4 + (local >> 4);
    const int pa = local & 15;
    const int b  = bh >> 4;
    const int nh = bh & 15;
    const size_t chan = (size_t)nh * 192;

    const int ksr = tid >> 2, ksc = tid & 3;
    const int vt0 = (tid & 31) * 2, vd0 = (tid >> 5) * 8;

    u16x8 kp0, kp1, vp0, vp1;   // prefetch registers

#pragma unroll
    for (int half = 0; half < 2; half++) {
        const int qt = half ? (31 - pa) : pa;
        const int qb = qt * 64;

        short8 qf0, qf1;
        {
            const int qrow = qb + wid * 16 + mr;
            const unsigned short* gq = qkv + ((size_t)(qrow * 2 + b)) * 3072 + chan + quad * 8;
            qf0 = *(const short8*)gq;
            qf1 = *(const short8*)(gq + 32);
        }

        const f32x4 zero = {0.f, 0.f, 0.f, 0.f};
        f32x4 o[4];
        float ps = 0.f;
#pragma unroll
        for (int d = 0; d < 4; d++) o[d] = zero;

        {
            const unsigned short* gk = qkv + ((size_t)(ksr * 2 + b)) * 3072 + chan + 64 + ksc * 16;
            kp0 = *(const u16x8*)gk;
            kp1 = *(const u16x8*)(gk + 8);
            const unsigned short* gv = qkv + ((size_t)(vt0 * 2 + b)) * 3072 + chan + 128 + vd0;
            vp0 = *(const u16x8*)gv;
            vp1 = *(const u16x8*)(gv + 6144);
        }

        for (int kt = 0; kt <= qt; kt++) {
            __syncthreads();
            *(u16x8*)(Ks + ksr * KSTR + ksc * 16) = kp0;
            *(u16x8*)(Ks + ksr * KSTR + ksc * 16 + 8) = kp1;
#pragma unroll
            for (int j = 0; j < 8; j++) {
                u16x2 pr; pr.x = vp0[j]; pr.y = vp1[j];
                *(u16x2*)(Vs + (vd0 + j) * KSTR + vt0) = pr;
            }
            if (kt < qt) {
                const int nb = (kt + 1) * 64;
                const unsigned short* gk =
                    qkv + ((size_t)((nb + ksr) * 2 + b)) * 3072 + chan + 64 + ksc * 16;
                kp0 = *(const u16x8*)gk;
                kp1 = *(const u16x8*)(gk + 8);
                const unsigned short* gv =
                    qkv + ((size_t)((nb + vt0) * 2 + b)) * 3072 + chan + 128 + vd0;
                vp0 = *(const u16x8*)gv;
                vp1 = *(const u16x8*)(gv + 6144);
            }
            __syncthreads();

            // ---- S^T = K Q^T: lane owns q=mr, t = n*16 + quad*4 + r ----
            f32x4 sacc[4];
#pragma unroll
            for (int n = 0; n < 4; n++) {
                sacc[n] = zero;
                const unsigned short* kb = Ks + (n * 16 + mr) * KSTR + quad * 8;
                short8 kfr0 = *(const short8*)kb;
                short8 kfr1 = *(const short8*)(kb + 32);
                sacc[n] = __builtin_amdgcn_mfma_f32_16x16x32_bf16(kfr0, qf0, sacc[n], 0, 0, 0);
                sacc[n] = __builtin_amdgcn_mfma_f32_16x16x32_bf16(kfr1, qf1, sacc[n], 0, 0, 0);
            }
            if (kt == qt) {
#pragma unroll
                for (int n = 0; n < 4; n++)
#pragma unroll
                    for (int r = 0; r < 4; r++)
                        if (n * 16 + quad * 4 + r > wid * 16 + mr) sacc[n][r] = -3.0e38f;
            }

            // ---- max-free softmax: p = 2^(s*SCL), clamped; fp32 row-partials ----
            unsigned short* prow = Ps + (wid * 16 + mr) * KSTR + quad * 4;
#pragma unroll
            for (int n = 0; n < 4; n++) {
                u16x4 pk;
#pragma unroll
                for (int r = 0; r < 4; r++) {
                    const float p = exp2f(fminf(sacc[n][r] * SCL, 80.f));
                    ps += p;
                    pk[r] = (unsigned short)(__float_as_uint(p) >> 16);
                }
                *(u16x4*)(prow + n * 16) = pk;
            }

            // ---- O^T += V^T P^T: lane owns q=mr, d = dblk*16 + quad*4 + r ----
            {
                const unsigned short* pb = Ps + (wid * 16 + mr) * KSTR + quad * 8;
                short8 pa0 = *(const short8*)pb;
                short8 pa1 = *(const short8*)(pb + 32);
#pragma unroll
                for (int d = 0; d < 4; d++) {
                    const unsigned short* vb = Vs + (d * 16 + mr) * KSTR + quad * 8;
                    short8 vf0 = *(const short8*)vb;
                    short8 vf1 = *(const short8*)(vb + 32);
                    o[d] = __builtin_amdgcn_mfma_f32_16x16x32_bf16(vf0, pa0, o[d], 0, 0, 0);
                    o[d] = __builtin_amdgcn_mfma_f32_16x16x32_bf16(vf1, pa1, o[d], 0, 0, 0);
                }
            }
        }

        // ---- epilogue: l[q=mr] via 2 shfl_xor; vectorized O store ----
        ps += __shfl_xor(ps, 16);
        ps += __shfl_xor(ps, 32);
        const float inv = 1.0f / ps;
        const int qrow = qb + wid * 16 + mr;
        unsigned short* po = out + ((size_t)(qrow * 2 + b)) * H_DIM + nh * HDIM;
#pragma unroll
        for (int d = 0; d < 4; d++) {
            u16x4 pk;
#pragma unroll
            for (int r = 0; r < 4; r++) pk[r] = f2bf(o[d][r] * inv);
            *(u16x4*)(po + d * 16 + quad * 4) = pk;
        }
    }
}

extern "C" void kernel_launch(void* const* d_in, const int* in_sizes, int n_in,
                              void* d_out, int out_size, void* d_ws, size_t ws_size,
                              hipStream_t stream) {
    const float* x      = (const float*)d_in[0];
    const float* ln1_w  = (const float*)d_in[1];
    const float* ln1_b  = (const float*)d_in[2];
    const float* w_qkv  = (const float*)d_in[3];
    const float* b_qkv  = (const float*)d_in[4];
    const float* w_proj = (const float*)d_in[5];
    const float* b_proj = (const float*)d_in[6];
    const float* ln2_w  = (const float*)d_in[7];
    const float* ln2_b  = (const float*)d_in[8];
    const float* w_fc1  = (const float*)d_in[9];
    const float* b_fc1  = (const float*)d_in[10];
    const float* w_fc2  = (const float*)d_in[11];
    const float* b_fc2  = (const float*)d_in[12];
    float* out = (float*)d_out;

    char* ws = (char*)d_ws;
    unsigned short* wqkv_bf  = (unsigned short*)(ws);                        // 6 MB (packed)
    unsigned short* wproj_bf = (unsigned short*)(ws + ((size_t)6 << 20));    // 2 MB (packed)
    unsigned short* wfc1_bf  = (unsigned short*)(ws + ((size_t)8 << 20));    // 8 MB (packed)
    unsigned short* wfc2_bf  = (unsigned short*)(ws + ((size_t)16 << 20));   // 8 MB (packed)
    unsigned short* ln_buf   = (unsigned short*)(ws + ((size_t)24 << 20));   // 8 MB
    unsigned short* qkv_bf   = (unsigned short*)(ws + ((size_t)32 << 20));   // 24 MB
    unsigned short* attn_bf  = (unsigned short*)(ws + ((size_t)56 << 20));   // 8 MB
    unsigned short* fc1_bf   = (unsigned short*)(ws + ((size_t)32 << 20));   // 32 MB (qkv/attn dead)

    cast_pack<<<6144, 256, 0, stream>>>(w_qkv, w_proj, w_fc1, w_fc2,
                                        wqkv_bf, wproj_bf, wfc1_bf, wfc2_bf);

    // 1) LN1 -> bf16
    ln_bf16<<<M_ROWS, 256, 0, stream>>>(x, ln1_w, ln1_b, ln_buf);
    // 2) qkv = ln1 @ w_qkv^T + b_qkv   [4096,3072] bf16   (768 blocks)
    gemm_qkv<<<768, 256, 0, stream>>>(ln_buf, wqkv_bf, b_qkv, qkv_bf,
                                      M_ROWS, 3072, 1024);
    // 3) MFMA flash attention -> bf16 [4096,1024]   (512 blocks, XCD-local)
    attn_mfma<<<512, 256, 0, stream>>>(qkv_bf, attn_bf);
    // 4) x1 = x + attn @ w_proj^T + b_proj  -> d_out (fp32)   (512 blocks)
    gemm_proj<<<512, 256, 0, stream>>>(attn_bf, wproj_bf, b_proj, x, out,
                                       M_ROWS, 1024, 1024);
    // 5) LN2 -> bf16
    ln_bf16<<<M_ROWS, 256, 0, stream>>>(out, ln2_w, ln2_b, ln_buf);
    // 6) fc1 + gelu -> bf16 [4096,4096]   (1024 blocks)
    gemm_fc1<<<1024, 256, 0, stream>>>(ln_buf, wfc1_bf, b_fc1, fc1_bf,
                                       M_ROWS, 4096, 1024);
    // 7) out = x1 + fc1 @ w_fc2^T + b_fc2 (in-place residual)   (512 blocks)
    gemm_fc2<<<512, 256, 0, stream>>>(fc1_bf, wfc2_bf, b_fc2, out, out,
                                      M_ROWS, 1024, 4096);
}